// Round 6
// baseline (446.663 us; speedup 1.0000x reference)
//
#include <hip/hip_runtime.h>
#include <hip/hip_bf16.h>
#include <math.h>

// Problem shape (fixed by reference setup_inputs): B=8, L=2048, D=1024, n=16, d=64
#define BATCH 8
#define SEQL  2048
#define DIM   1024
#define NHEAD 16
#define HDIM  64
#define MROWS (BATCH * SEQL)   // 16384

typedef _Float16 f16;
typedef _Float16 f16x8 __attribute__((ext_vector_type(8)));
typedef _Float16 f16x4 __attribute__((ext_vector_type(4)));
typedef float f32x4 __attribute__((ext_vector_type(4)));

// ---------------------------------------------------------------------------
// fp32 -> f16 convert, 8 elems/thread, vectorized
__global__ __launch_bounds__(256) void cvt_f32_f16(const float* __restrict__ in,
                                                   f16* __restrict__ out, int n8)
{
    const int i = blockIdx.x * 256 + threadIdx.x;
    if (i >= n8) return;
    const float4* p = (const float4*)in + (size_t)i * 2;
    const float4 a = p[0], b = p[1];
    f16x8 v;
    v[0] = (f16)a.x; v[1] = (f16)a.y; v[2] = (f16)a.z; v[3] = (f16)a.w;
    v[4] = (f16)b.x; v[5] = (f16)b.y; v[6] = (f16)b.z; v[7] = (f16)b.w;
    *(f16x8*)(out + (size_t)i * 8) = v;
}

// ---------------------------------------------------------------------------
// f16 MFMA GEMM (m97 structure): C[m,n] = sum_k A[m,k]*Bw[n,k]
// 128x128 tile, BK=64, 4 waves (2x2), 64x64/wave, 16x16x32 MFMA,
// global_load_lds width-16 staging, 2-barrier K-loop, bijective XCD swizzle.
// MODE 0: fp32 C0 out, N=1024 (final projection)
// MODE 1: N=2048 split epilogue: col<1024 -> f16 C0 (k); col>=1024 -> sigmoid(+bias) f16 C1 (g)
template<int MODE>
__global__ __launch_bounds__(256) void gemm_mfma(const f16* __restrict__ A,
                                                 const f16* __restrict__ Bw,
                                                 const float* __restrict__ bias,
                                                 void* __restrict__ C0,
                                                 void* __restrict__ C1)
{
    constexpr int K  = DIM;
    constexpr int NT = MODE ? 16 : 8;     // 128-col panels
    __shared__ f16 Alds[128 * 64];
    __shared__ f16 Blds[128 * 64];

    const int tid = threadIdx.x;
    const int w = tid >> 6;
    const int l = tid & 63;

    // bijective XCD swizzle (nwg % 8 == 0)
    const int cpx = gridDim.x >> 3;
    const int lt  = (blockIdx.x & 7) * cpx + (blockIdx.x >> 3);
    const int bm  = (lt / NT) * 128;
    const int bn  = (lt % NT) * 128;

    // staging: per wave-call, 64 lanes x 16B = 8 rows of BK=64
    const int sr = w * 32 + (l >> 3);
    const int sc = (l & 7) * 8;
    const size_t gaA = (size_t)(bm + sr) * K + sc;
    const size_t gaB = (size_t)(bn + sr) * K + sc;
    const int le = w * 2048 + l * 8;

    const int wr = (w >> 1) * 64;
    const int wc = (w & 1) * 64;
    const int lrow = l & 15;
    const int lko  = (l >> 4) * 8;

    f32x4 acc[4][4];
    #pragma unroll
    for (int mi = 0; mi < 4; ++mi)
        #pragma unroll
        for (int ni = 0; ni < 4; ++ni) acc[mi][ni] = (f32x4){0.f, 0.f, 0.f, 0.f};

    for (int k0 = 0; k0 < K; k0 += 64) {
        __syncthreads();
        #pragma unroll
        for (int i = 0; i < 4; ++i)
            __builtin_amdgcn_global_load_lds(
                (const __attribute__((address_space(1))) void*)(A + gaA + (size_t)(i * 8) * K + k0),
                (__attribute__((address_space(3))) void*)(Alds + le + i * 512), 16, 0, 0);
        #pragma unroll
        for (int i = 0; i < 4; ++i)
            __builtin_amdgcn_global_load_lds(
                (const __attribute__((address_space(1))) void*)(Bw + gaB + (size_t)(i * 8) * K + k0),
                (__attribute__((address_space(3))) void*)(Blds + le + i * 512), 16, 0, 0);
        __syncthreads();

        #pragma unroll
        for (int ks = 0; ks < 2; ++ks) {
            f16x8 af[4], bf[4];
            #pragma unroll
            for (int mi = 0; mi < 4; ++mi)
                af[mi] = *(const f16x8*)(Alds + (wr + mi * 16 + lrow) * 64 + ks * 32 + lko);
            #pragma unroll
            for (int ni = 0; ni < 4; ++ni)
                bf[ni] = *(const f16x8*)(Blds + (wc + ni * 16 + lrow) * 64 + ks * 32 + lko);
            #pragma unroll
            for (int mi = 0; mi < 4; ++mi)
                #pragma unroll
                for (int ni = 0; ni < 4; ++ni)
                    acc[mi][ni] = __builtin_amdgcn_mfma_f32_16x16x32_f16(
                        af[mi], bf[ni], acc[mi][ni], 0, 0, 0);
        }
    }

    // epilogue: C/D layout col = l&15, row = (l>>4)*4 + reg
    const int orow = (l >> 4) * 4;
    const int ocol = l & 15;
    #pragma unroll
    for (int mi = 0; mi < 4; ++mi) {
        #pragma unroll
        for (int ni = 0; ni < 4; ++ni) {
            const int col = bn + wc + ni * 16 + ocol;
            #pragma unroll
            for (int r = 0; r < 4; ++r) {
                const int row = bm + wr + mi * 16 + orow + r;
                float v = acc[mi][ni][r];
                if (MODE == 0) {
                    ((float*)C0)[(size_t)row * DIM + col] = v;
                } else {
                    if (col < DIM) {
                        ((f16*)C0)[(size_t)row * DIM + col] = (f16)v;   // k
                    } else {
                        v += bias[col - DIM];
                        v = 1.f / (1.f + __expf(-v));                   // g
                        ((f16*)C1)[(size_t)row * DIM + (col - DIM)] = (f16)v;
                    }
                }
            }
        }
    }
}

// ---------------------------------------------------------------------------
// DPP-based cross-lane add (VALU latency). CTRL compile-time.
template<int CTRL>
__device__ __forceinline__ float dpp_add_f(float s) {
    int t = __builtin_amdgcn_update_dpp(0, __float_as_int(s), CTRL, 0xF, 0xF, true);
    return s + __int_as_float(t);
}

#define PF 8   // prefetch depth (steps)

// Scan, re-laid-out: 4 sequences per wave (rows of 16 lanes), 4 dims per lane
// (contiguous f16x4). Reduce = 4 row-local DPP butterfly steps (xor1/2/4/8,
// all-lane symmetric) -> every lane holds its sequence's full sum; no
// readlane, no scalar round-trip. inv = rsq(S/64 + 1e-20) replaces
// sqrt->add->rcp (eps change is <=1e-5 relative, far below f16 rounding).
// Wave w: batch w>>2, heads 4*(w&3).. +3; lane l: dims 4*l of that 256-chunk.
__global__ __launch_bounds__(64) void scan_kernel(f16* __restrict__ Kv,
                                                  const f16* __restrict__ Gv)
{
    const int w = blockIdx.x;     // 0..31
    const int l = threadIdx.x;

    const size_t base = (size_t)(w >> 2) * (SEQL * DIM) + (size_t)((w & 3) * 256 + l * 4);
    float h0 = 0.f, h1 = 0.f, h2 = 0.f, h3 = 0.f;

    f16x4 kb[PF], gb[PF];
    #pragma unroll
    for (int u = 0; u < PF; ++u) {
        kb[u] = *(const f16x4*)(Kv + base + (size_t)u * DIM);
        gb[u] = *(const f16x4*)(Gv + base + (size_t)u * DIM);
    }

    size_t off = base;

    #define SCAN_STEP(kc, gc)                                                          \
        do {                                                                           \
            const float k0 = (float)(kc)[0], k1 = (float)(kc)[1],                      \
                        k2 = (float)(kc)[2], k3 = (float)(kc)[3];                      \
            const float g0 = (float)(gc)[0], g1 = (float)(gc)[1],                      \
                        g2 = (float)(gc)[2], g3 = (float)(gc)[3];                      \
            const float u0 = h0 * g0, u1 = h1 * g1, u2 = h2 * g2, u3 = h3 * g3;        \
            float sa = h0 * h0, sb = h2 * h2;                                          \
            sa = fmaf(h1, h1, sa); sb = fmaf(h3, h3, sb);                              \
            float s = sa + sb;                                                         \
            s = dpp_add_f<0xB1>(s);   /* xor1: quad_perm [1,0,3,2] */                  \
            s = dpp_add_f<0x4E>(s);   /* xor2: quad_perm [2,3,0,1] */                  \
            s = dpp_add_f<0x141>(s);  /* xor4: row_half_mirror */                      \
            s = dpp_add_f<0x140>(s);  /* xor8: row_mirror */                           \
            const float inv = __builtin_amdgcn_rsqf(fmaf(s, 0.015625f, 1e-20f));       \
            h0 = fmaf(u0, inv, k0); h1 = fmaf(u1, inv, k1);                            \
            h2 = fmaf(u2, inv, k2); h3 = fmaf(u3, inv, k3);                            \
            f16x4 o; o[0] = (f16)h0; o[1] = (f16)h1; o[2] = (f16)h2; o[3] = (f16)h3;   \
            *(f16x4*)(Kv + off) = o;                                                   \
            off += DIM;                                                                \
        } while (0)

    for (int t0 = 0; t0 + PF < SEQL; t0 += PF) {
        #pragma unroll
        for (int u = 0; u < PF; ++u) {
            const f16x4 kc = kb[u], gc = gb[u];
            const size_t poff = off + (size_t)PF * DIM;   // refill PF ahead
            kb[u] = *(const f16x4*)(Kv + poff);
            gb[u] = *(const f16x4*)(Gv + poff);
            SCAN_STEP(kc, gc);
        }
    }
    #pragma unroll
    for (int u = 0; u < PF; ++u) {
        const f16x4 kc = kb[u], gc = gb[u];
        SCAN_STEP(kc, gc);
    }
    #undef SCAN_STEP
}

// ---------------------------------------------------------------------------
extern "C" void kernel_launch(void* const* d_in, const int* in_sizes, int n_in,
                              void* d_out, int out_size, void* d_ws, size_t ws_size,
                              hipStream_t stream) {
    const float* x    = (const float*)d_in[0];   // [B,L,D]
    const float* Wk   = (const float*)d_in[1];   // [D,D]
    const float* Wkg  = (const float*)d_in[2];   // [D,D]
    const float* bkg  = (const float*)d_in[3];   // [D]
    const float* Wout = (const float*)d_in[4];   // [D,D]
    float* out = (float*)d_out;                  // [B,L,D] fp32

    // workspace (f16): 3*32MB + 4MB + 2MB = 102MB
    f16* xh    = (f16*)d_ws;                         // [M, D]
    f16* Kh    = xh    + (size_t)MROWS * DIM;        // [M, D] (scan in-place)
    f16* Gh    = Kh    + (size_t)MROWS * DIM;        // [M, D]
    f16* Wcat  = Gh    + (size_t)MROWS * DIM;        // [2048, 1024]: Wk ; Wkg
    f16* Wouth = Wcat  + (size_t)2 * DIM * DIM;      // [D, D]

    const int nx8 = MROWS * DIM / 8;
    const int nw8 = DIM * DIM / 8;
    cvt_f32_f16<<<dim3(nx8 / 256), dim3(256), 0, stream>>>(x, xh, nx8);
    cvt_f32_f16<<<dim3(nw8 / 256), dim3(256), 0, stream>>>(Wk, Wcat, nw8);
    cvt_f32_f16<<<dim3(nw8 / 256), dim3(256), 0, stream>>>(Wkg, Wcat + (size_t)DIM * DIM, nw8);
    cvt_f32_f16<<<dim3(nw8 / 256), dim3(256), 0, stream>>>(Wout, Wouth, nw8);

    const dim3 gblk(256);

    // fused: k | g = x @ [Wk;Wkg].T, split epilogue (k f16, g sigmoid f16)
    gemm_mfma<1><<<dim3((MROWS / 128) * 16), gblk, 0, stream>>>(xh, Wcat, bkg, Kh, Gh);
    // sequential scan, o overwrites Kh
    scan_kernel<<<dim3(32), dim3(64), 0, stream>>>(Kh, Gh);
    // out = o @ Wout.T (fp32)
    gemm_mfma<0><<<dim3((MROWS / 128) * 8), gblk, 0, stream>>>(Kh, Wouth, nullptr, out, nullptr);
}

// Round 7
// 342.191 us; speedup vs baseline: 1.3053x; 1.3053x over previous
//
#include <hip/hip_runtime.h>
#include <hip/hip_bf16.h>
#include <math.h>

// Problem shape (fixed by reference setup_inputs): B=8, L=2048, D=1024, n=16, d=64
#define BATCH 8
#define SEQL  2048
#define DIM   1024
#define NHEAD 16
#define HDIM  64
#define MROWS (BATCH * SEQL)   // 16384

typedef _Float16 f16;
typedef _Float16 f16x8 __attribute__((ext_vector_type(8)));
typedef _Float16 f16x4 __attribute__((ext_vector_type(4)));
typedef _Float16 f16x2 __attribute__((ext_vector_type(2)));
typedef float f32x4 __attribute__((ext_vector_type(4)));

// ---------------------------------------------------------------------------
// fp32 -> f16 convert, 8 elems/thread, vectorized
__global__ __launch_bounds__(256) void cvt_f32_f16(const float* __restrict__ in,
                                                   f16* __restrict__ out, int n8)
{
    const int i = blockIdx.x * 256 + threadIdx.x;
    if (i >= n8) return;
    const float4* p = (const float4*)in + (size_t)i * 2;
    const float4 a = p[0], b = p[1];
    f16x8 v;
    v[0] = (f16)a.x; v[1] = (f16)a.y; v[2] = (f16)a.z; v[3] = (f16)a.w;
    v[4] = (f16)b.x; v[5] = (f16)b.y; v[6] = (f16)b.z; v[7] = (f16)b.w;
    *(f16x8*)(out + (size_t)i * 8) = v;
}

// ---------------------------------------------------------------------------
// f16 MFMA GEMM (m97 structure): C[m,n] = sum_k A[m,k]*Bw[n,k]
// 128x128 tile, BK=64, 4 waves (2x2), 64x64/wave, 16x16x32 MFMA,
// global_load_lds width-16 staging, 2-barrier K-loop, bijective XCD swizzle.
// MODE 0: fp32 C0 out, N=1024 (final projection)
// MODE 1: N=2048 split epilogue: col<1024 -> f16 C0 (k); col>=1024 -> sigmoid(+bias) f16 C1 (g)
template<int MODE>
__global__ __launch_bounds__(256) void gemm_mfma(const f16* __restrict__ A,
                                                 const f16* __restrict__ Bw,
                                                 const float* __restrict__ bias,
                                                 void* __restrict__ C0,
                                                 void* __restrict__ C1)
{
    constexpr int K  = DIM;
    constexpr int NT = MODE ? 16 : 8;     // 128-col panels
    __shared__ f16 Alds[128 * 64];
    __shared__ f16 Blds[128 * 64];

    const int tid = threadIdx.x;
    const int w = tid >> 6;
    const int l = tid & 63;

    // bijective XCD swizzle (nwg % 8 == 0)
    const int cpx = gridDim.x >> 3;
    const int lt  = (blockIdx.x & 7) * cpx + (blockIdx.x >> 3);
    const int bm  = (lt / NT) * 128;
    const int bn  = (lt % NT) * 128;

    // staging: per wave-call, 64 lanes x 16B = 8 rows of BK=64
    const int sr = w * 32 + (l >> 3);
    const int sc = (l & 7) * 8;
    const size_t gaA = (size_t)(bm + sr) * K + sc;
    const size_t gaB = (size_t)(bn + sr) * K + sc;
    const int le = w * 2048 + l * 8;

    const int wr = (w >> 1) * 64;
    const int wc = (w & 1) * 64;
    const int lrow = l & 15;
    const int lko  = (l >> 4) * 8;

    f32x4 acc[4][4];
    #pragma unroll
    for (int mi = 0; mi < 4; ++mi)
        #pragma unroll
        for (int ni = 0; ni < 4; ++ni) acc[mi][ni] = (f32x4){0.f, 0.f, 0.f, 0.f};

    for (int k0 = 0; k0 < K; k0 += 64) {
        __syncthreads();
        #pragma unroll
        for (int i = 0; i < 4; ++i)
            __builtin_amdgcn_global_load_lds(
                (const __attribute__((address_space(1))) void*)(A + gaA + (size_t)(i * 8) * K + k0),
                (__attribute__((address_space(3))) void*)(Alds + le + i * 512), 16, 0, 0);
        #pragma unroll
        for (int i = 0; i < 4; ++i)
            __builtin_amdgcn_global_load_lds(
                (const __attribute__((address_space(1))) void*)(Bw + gaB + (size_t)(i * 8) * K + k0),
                (__attribute__((address_space(3))) void*)(Blds + le + i * 512), 16, 0, 0);
        __syncthreads();

        #pragma unroll
        for (int ks = 0; ks < 2; ++ks) {
            f16x8 af[4], bf[4];
            #pragma unroll
            for (int mi = 0; mi < 4; ++mi)
                af[mi] = *(const f16x8*)(Alds + (wr + mi * 16 + lrow) * 64 + ks * 32 + lko);
            #pragma unroll
            for (int ni = 0; ni < 4; ++ni)
                bf[ni] = *(const f16x8*)(Blds + (wc + ni * 16 + lrow) * 64 + ks * 32 + lko);
            #pragma unroll
            for (int mi = 0; mi < 4; ++mi)
                #pragma unroll
                for (int ni = 0; ni < 4; ++ni)
                    acc[mi][ni] = __builtin_amdgcn_mfma_f32_16x16x32_f16(
                        af[mi], bf[ni], acc[mi][ni], 0, 0, 0);
        }
    }

    // epilogue: C/D layout col = l&15, row = (l>>4)*4 + reg
    const int orow = (l >> 4) * 4;
    const int ocol = l & 15;
    #pragma unroll
    for (int mi = 0; mi < 4; ++mi) {
        #pragma unroll
        for (int ni = 0; ni < 4; ++ni) {
            const int col = bn + wc + ni * 16 + ocol;
            #pragma unroll
            for (int r = 0; r < 4; ++r) {
                const int row = bm + wr + mi * 16 + orow + r;
                float v = acc[mi][ni][r];
                if (MODE == 0) {
                    ((float*)C0)[(size_t)row * DIM + col] = v;
                } else {
                    if (col < DIM) {
                        ((f16*)C0)[(size_t)row * DIM + col] = (f16)v;   // k
                    } else {
                        v += bias[col - DIM];
                        v = 1.f / (1.f + __expf(-v));                   // g
                        ((f16*)C1)[(size_t)row * DIM + (col - DIM)] = (f16)v;
                    }
                }
            }
        }
    }
}

// ---------------------------------------------------------------------------
// DPP-based cross-lane add (VALU latency). CTRL compile-time.
template<int CTRL>
__device__ __forceinline__ float dpp_add_f(float s) {
    int t = __builtin_amdgcn_update_dpp(0, __float_as_int(s), CTRL, 0xF, 0xF, true);
    return s + __int_as_float(t);
}

__device__ __forceinline__ float sumsq4(f16x2 a, f16x2 b) {
#if __has_builtin(__builtin_amdgcn_fdot2)
    return __builtin_amdgcn_fdot2(a, a, __builtin_amdgcn_fdot2(b, b, 0.f, false), false);
#else
    return (float)a[0] * (float)a[0] + (float)a[1] * (float)a[1]
         + (float)b[0] * (float)b[0] + (float)b[1] * (float)b[1];
#endif
}

#define PF 16   // prefetch depth (steps): 16-step window covers ~1200+cy latency

// Scan: 4 sequences per wave (16-lane rows), 4 dims per lane (f16x4).
// Packed-f16 state: squares via fdot2, gate/update via v_pk_mul/v_pk_fma,
// 4-hop row-local DPP butterfly for the 16-lane reduce (all-lane symmetric,
// no readlane). inv = rsq(S/64 + 1e-8) — eps floor keeps inv <= 1e4, finite
// in f16, so t=0 (h=0) gives 0*inv = 0, h1 = k exactly.
// Reads Kv/Gv (read-only), writes o to a separate buffer Ov.
__global__ __launch_bounds__(64) void scan_kernel(const f16* __restrict__ Kv,
                                                  const f16* __restrict__ Gv,
                                                  f16* __restrict__ Ov)
{
    const int w = blockIdx.x;     // 0..31
    const int l = threadIdx.x;

    const size_t base = (size_t)(w >> 2) * (SEQL * DIM) + (size_t)((w & 3) * 256 + l * 4);
    f16x2 h01 = (f16x2){(f16)0.f, (f16)0.f};
    f16x2 h23 = (f16x2){(f16)0.f, (f16)0.f};

    f16x4 kb[PF], gb[PF];
    #pragma unroll
    for (int u = 0; u < PF; ++u) {
        kb[u] = *(const f16x4*)(Kv + base + (size_t)u * DIM);
        gb[u] = *(const f16x4*)(Gv + base + (size_t)u * DIM);
    }

    size_t off = base;

    #define SCAN_STEP(kc, gc)                                                          \
        do {                                                                           \
            const f16x2 k01 = __builtin_shufflevector((kc), (kc), 0, 1);               \
            const f16x2 k23 = __builtin_shufflevector((kc), (kc), 2, 3);               \
            const f16x2 g01 = __builtin_shufflevector((gc), (gc), 0, 1);               \
            const f16x2 g23 = __builtin_shufflevector((gc), (gc), 2, 3);               \
            const f16x2 u01 = h01 * g01;   /* v_pk_mul_f16 */                          \
            const f16x2 u23 = h23 * g23;                                               \
            float s = sumsq4(h01, h23);                                                \
            s = dpp_add_f<0xB1>(s);   /* xor1: quad_perm [1,0,3,2] */                  \
            s = dpp_add_f<0x4E>(s);   /* xor2: quad_perm [2,3,0,1] */                  \
            s = dpp_add_f<0x141>(s);  /* xor4: row_half_mirror */                      \
            s = dpp_add_f<0x140>(s);  /* xor8: row_mirror */                           \
            const float inv = __builtin_amdgcn_rsqf(fmaf(s, 0.015625f, 1e-8f));        \
            const f16 ih = (f16)inv;                                                   \
            const f16x2 iv = (f16x2){ih, ih};                                          \
            h01 = u01 * iv + k01;     /* v_pk_fma_f16 */                               \
            h23 = u23 * iv + k23;                                                      \
            f16x4 o;                                                                   \
            o[0] = h01[0]; o[1] = h01[1]; o[2] = h23[0]; o[3] = h23[1];                \
            *(f16x4*)(Ov + off) = o;                                                   \
            off += DIM;                                                                \
        } while (0)

    for (int t0 = 0; t0 + PF < SEQL; t0 += PF) {
        #pragma unroll
        for (int u = 0; u < PF; ++u) {
            const f16x4 kc = kb[u], gc = gb[u];
            const size_t poff = off + (size_t)PF * DIM;   // refill PF ahead
            kb[u] = *(const f16x4*)(Kv + poff);
            gb[u] = *(const f16x4*)(Gv + poff);
            SCAN_STEP(kc, gc);
        }
    }
    #pragma unroll
    for (int u = 0; u < PF; ++u) {
        const f16x4 kc = kb[u], gc = gb[u];
        SCAN_STEP(kc, gc);
    }
    #undef SCAN_STEP
}

// ---------------------------------------------------------------------------
extern "C" void kernel_launch(void* const* d_in, const int* in_sizes, int n_in,
                              void* d_out, int out_size, void* d_ws, size_t ws_size,
                              hipStream_t stream) {
    const float* x    = (const float*)d_in[0];   // [B,L,D]
    const float* Wk   = (const float*)d_in[1];   // [D,D]
    const float* Wkg  = (const float*)d_in[2];   // [D,D]
    const float* bkg  = (const float*)d_in[3];   // [D]
    const float* Wout = (const float*)d_in[4];   // [D,D]
    float* out = (float*)d_out;                  // [B,L,D] fp32

    // workspace (f16): xh/Kh/Gh 32MB each + Wcat 4MB + Wout 2MB = 102MB
    f16* xh    = (f16*)d_ws;                         // [M, D]; scan output reuses it
    f16* Kh    = xh    + (size_t)MROWS * DIM;        // [M, D]
    f16* Gh    = Kh    + (size_t)MROWS * DIM;        // [M, D]
    f16* Wcat  = Gh    + (size_t)MROWS * DIM;        // [2048, 1024]: Wk ; Wkg
    f16* Wouth = Wcat  + (size_t)2 * DIM * DIM;      // [D, D]

    const int nx8 = MROWS * DIM / 8;
    const int nw8 = DIM * DIM / 8;
    cvt_f32_f16<<<dim3(nx8 / 256), dim3(256), 0, stream>>>(x, xh, nx8);
    cvt_f32_f16<<<dim3(nw8 / 256), dim3(256), 0, stream>>>(Wk, Wcat, nw8);
    cvt_f32_f16<<<dim3(nw8 / 256), dim3(256), 0, stream>>>(Wkg, Wcat + (size_t)DIM * DIM, nw8);
    cvt_f32_f16<<<dim3(nw8 / 256), dim3(256), 0, stream>>>(Wout, Wouth, nw8);

    const dim3 gblk(256);

    // fused: k | g = x @ [Wk;Wkg].T, split epilogue (k f16, g sigmoid f16)
    gemm_mfma<1><<<dim3((MROWS / 128) * 16), gblk, 0, stream>>>(xh, Wcat, bkg, Kh, Gh);
    // sequential scan: o -> xh (xh is dead after kg-GEMM)
    scan_kernel<<<dim3(32), dim3(64), 0, stream>>>(Kh, Gh, xh);
    // out = o @ Wout.T (fp32)
    gemm_mfma<0><<<dim3((MROWS / 128) * 8), gblk, 0, stream>>>(xh, Wouth, nullptr, out, nullptr);
}

// Round 8
// 293.829 us; speedup vs baseline: 1.5201x; 1.1646x over previous
//
#include <hip/hip_runtime.h>
#include <hip/hip_bf16.h>
#include <math.h>

// Problem shape (fixed): B=8, L=2048, D=1024, n=16, d=64
#define BATCH 8
#define SEQL  2048
#define DIM   1024
#define NHEAD 16
#define MROWS (BATCH * SEQL)   // 16384

typedef _Float16 f16;
typedef _Float16 f16x8 __attribute__((ext_vector_type(8)));
typedef _Float16 f16x4 __attribute__((ext_vector_type(4)));
typedef _Float16 f16x2 __attribute__((ext_vector_type(2)));
typedef float f32x4 __attribute__((ext_vector_type(4)));

typedef const __attribute__((address_space(1))) void* gp_t;
typedef __attribute__((address_space(3))) void* lp_t;
#define GLL(src, dst) __builtin_amdgcn_global_load_lds((gp_t)(src), (lp_t)(dst), 16, 0, 0)

// ---------------------------------------------------------------------------
// fp32 -> f16 convert, 8 elems/thread
__global__ __launch_bounds__(256) void cvt_f32_f16(const float* __restrict__ in,
                                                   f16* __restrict__ out, int n8)
{
    const int i = blockIdx.x * 256 + threadIdx.x;
    if (i >= n8) return;
    const float4* p = (const float4*)in + (size_t)i * 2;
    const float4 a = p[0], b = p[1];
    f16x8 v;
    v[0] = (f16)a.x; v[1] = (f16)a.y; v[2] = (f16)a.z; v[3] = (f16)a.w;
    v[4] = (f16)b.x; v[5] = (f16)b.y; v[6] = (f16)b.z; v[7] = (f16)b.w;
    *(f16x8*)(out + (size_t)i * 8) = v;
}

// ---------------------------------------------------------------------------
// 256x256-tile 8-phase f16 MFMA GEMM (m201-style: T3+T4 counted vmcnt, T2
// swizzle via inverse-swizzled global source, T5 setprio).
// C[m,n] = sum_k A[m,k]*Bw[n,k]. K=1024 fixed. 512 threads = 8 waves (2Mx4N),
// each wave owns 128x64 of C (acc[8][4] f32x4). BK=64, 2 LDS buffers (128KB).
// Per K-tile: 4 phases; phase p computes C-quadrant mi={2p,2p+1} (16 MFMA),
// ds-reads its A-frags (+all B-frags at p0, held in regs), stages one
// half-tile: p0/p1 -> A(t+1) (over dead A(t-1)), p2/p3 -> B(t+2) (over B(t),
// dead after p0). One s_waitcnt vmcnt(4) per K-tile (never 0 mid-loop).
// LDS granule swizzle: slot g at row r holds source granule g^(r&7); reads
// apply the same XOR -> per-bank depth 16 -> 8 (b128 baseline).
// MODE 0: fp32 C0, N=1024.  MODE 1: N=2048 split: col<1024 -> f16 k (C0),
// col>=1024 -> sigmoid(+bias) f16 g (C1).
template<int MODE>
__global__ __launch_bounds__(512, 2) void gemm8(const f16* __restrict__ A,
                                                const f16* __restrict__ Bw,
                                                const float* __restrict__ bias,
                                                void* __restrict__ C0,
                                                void* __restrict__ C1)
{
    constexpr int K   = 1024;
    constexpr int NTI = MODE ? 8 : 4;   // N/256
    constexpr int NKT = 16;             // K/64
    __shared__ f16 lds[2][2][256 * 64]; // [buf][A=0/B=1], 128 KiB

    const int tid = threadIdx.x;
    const int w = tid >> 6, l = tid & 63;
    const int wm = w >> 2, wn = w & 3;
    const int lrow = l & 15;
    const int l7 = l & 7, lk = l >> 4;

    // bijective XCD swizzle (grid % 8 == 0)
    const int cpx = gridDim.x >> 3;
    const int lt  = (blockIdx.x & 7) * cpx + (blockIdx.x >> 3);
    const int bm  = (lt / NTI) * 256;
    const int bn  = (lt % NTI) * 256;

    // staging geometry: 512 threads x 2 x 16B = one 128x64 half-tile
    const int srl   = tid >> 3;                 // 0..63 row within 64-row round
    const int sg    = tid & 7;                  // LDS granule slot
    const int scolx = (sg ^ (srl & 7)) * 8;     // inverse-swizzled source col

    // swizzled ds-read granule offsets (elems) for ks=0/1
    const int g0 = ((lk) ^ l7) * 8;
    const int g1 = ((4 + lk) ^ l7) * 8;

#define STAGE(t, m, P, rowbase, h)                                                       \
    do {                                                                                 \
        const int _rf0 = (h) * 128 + srl;                                                \
        GLL((P) + (size_t)((rowbase) + _rf0) * K + (t) * 64 + scolx,                     \
            &lds[(t) & 1][m][_rf0 * 64 + sg * 8]);                                       \
        const int _rf1 = _rf0 + 64;                                                      \
        GLL((P) + (size_t)((rowbase) + _rf1) * K + (t) * 64 + scolx,                     \
            &lds[(t) & 1][m][_rf1 * 64 + sg * 8]);                                       \
    } while (0)

    f32x4 acc[8][4];
    #pragma unroll
    for (int mi = 0; mi < 8; ++mi)
        #pragma unroll
        for (int ni = 0; ni < 4; ++ni) acc[mi][ni] = (f32x4){0.f, 0.f, 0.f, 0.f};

    f16x8 bf[4][2];

#define PHASE(p, cur, STG, LOAD_B)                                                       \
    do {                                                                                 \
        const f16* _ab = &lds[cur][0][0];                                                \
        const int _ar = (wm * 128 + (2 * (p)) * 16 + lrow) * 64;                         \
        f16x8 a00 = *(const f16x8*)(_ab + _ar + g0);                                     \
        f16x8 a01 = *(const f16x8*)(_ab + _ar + g1);                                     \
        f16x8 a10 = *(const f16x8*)(_ab + _ar + 1024 + g0);                              \
        f16x8 a11 = *(const f16x8*)(_ab + _ar + 1024 + g1);                              \
        if (LOAD_B) {                                                                    \
            const f16* _bb = &lds[cur][1][0];                                            \
            _Pragma("unroll")                                                            \
            for (int ni = 0; ni < 4; ++ni) {                                             \
                const int _br = (wn * 64 + ni * 16 + lrow) * 64;                         \
                bf[ni][0] = *(const f16x8*)(_bb + _br + g0);                             \
                bf[ni][1] = *(const f16x8*)(_bb + _br + g1);                             \
            }                                                                            \
        }                                                                                \
        STG;                                                                             \
        __builtin_amdgcn_s_barrier();                                                    \
        asm volatile("s_waitcnt lgkmcnt(0)" ::: "memory");                               \
        __builtin_amdgcn_sched_barrier(0);                                               \
        __builtin_amdgcn_s_setprio(1);                                                   \
        _Pragma("unroll")                                                                \
        for (int ni = 0; ni < 4; ++ni) {                                                 \
            acc[2*(p)][ni]   = __builtin_amdgcn_mfma_f32_16x16x32_f16(a00, bf[ni][0], acc[2*(p)][ni], 0, 0, 0);   \
            acc[2*(p)][ni]   = __builtin_amdgcn_mfma_f32_16x16x32_f16(a01, bf[ni][1], acc[2*(p)][ni], 0, 0, 0);   \
            acc[2*(p)+1][ni] = __builtin_amdgcn_mfma_f32_16x16x32_f16(a10, bf[ni][0], acc[2*(p)+1][ni], 0, 0, 0); \
            acc[2*(p)+1][ni] = __builtin_amdgcn_mfma_f32_16x16x32_f16(a11, bf[ni][1], acc[2*(p)+1][ni], 0, 0, 0); \
        }                                                                                \
        __builtin_amdgcn_s_setprio(0);                                                   \
    } while (0)

    // prologue: A(0),B(0),B(1); wait A(0)+B(0) (first 8 of 12 loads)
    STAGE(0, 0, A, bm, 0);  STAGE(0, 0, A, bm, 1);
    STAGE(0, 1, Bw, bn, 0); STAGE(0, 1, Bw, bn, 1);
    STAGE(1, 1, Bw, bn, 0); STAGE(1, 1, Bw, bn, 1);
    asm volatile("s_waitcnt vmcnt(4)" ::: "memory");
    __builtin_amdgcn_s_barrier();

    for (int t = 0; t < NKT; ++t) {
        const int cur = t & 1;
        PHASE(0, cur, { if (t + 1 < NKT) STAGE(t + 1, 0, A, bm, 0); }, 1);
        __builtin_amdgcn_s_barrier();
        PHASE(1, cur, { if (t + 1 < NKT) STAGE(t + 1, 0, A, bm, 1); }, 0);
        __builtin_amdgcn_s_barrier();
        PHASE(2, cur, { if (t + 2 < NKT) STAGE(t + 2, 1, Bw, bn, 0); }, 0);
        __builtin_amdgcn_s_barrier();
        PHASE(3, cur, { if (t + 2 < NKT) STAGE(t + 2, 1, Bw, bn, 1); }, 0);
        if (t + 2 < NKT)      asm volatile("s_waitcnt vmcnt(4)" ::: "memory");
        else if (t + 1 < NKT) asm volatile("s_waitcnt vmcnt(0)" ::: "memory");
        __builtin_amdgcn_s_barrier();
    }
#undef PHASE
#undef STAGE

    // epilogue: C/D layout col = l&15, row = (l>>4)*4 + r
    const int orow = (l >> 4) * 4;
    const int ocol = l & 15;
    #pragma unroll
    for (int mi = 0; mi < 8; ++mi) {
        #pragma unroll
        for (int ni = 0; ni < 4; ++ni) {
            const int col  = bn + wn * 64 + ni * 16 + ocol;
            const int row0 = bm + wm * 128 + mi * 16 + orow;
            #pragma unroll
            for (int r = 0; r < 4; ++r) {
                float v = acc[mi][ni][r];
                if (MODE == 0) {
                    ((float*)C0)[(size_t)(row0 + r) * DIM + col] = v;
                } else {
                    if (col < DIM) {
                        ((f16*)C0)[(size_t)(row0 + r) * DIM + col] = (f16)v;     // k
                    } else {
                        v += bias[col - DIM];
                        v = 1.f / (1.f + __expf(-v));                            // g
                        ((f16*)C1)[(size_t)(row0 + r) * DIM + (col - DIM)] = (f16)v;
                    }
                }
            }
        }
    }
}

// ---------------------------------------------------------------------------
// DPP cross-lane add (VALU latency). CTRL compile-time.
template<int CTRL>
__device__ __forceinline__ float dpp_add_f(float s) {
    int t = __builtin_amdgcn_update_dpp(0, __float_as_int(s), CTRL, 0xF, 0xF, true);
    return s + __int_as_float(t);
}

__device__ __forceinline__ float sumsq4(f16x2 a, f16x2 b) {
#if __has_builtin(__builtin_amdgcn_fdot2)
    return __builtin_amdgcn_fdot2(a, a, __builtin_amdgcn_fdot2(b, b, 0.f, false), false);
#else
    return (float)a[0] * (float)a[0] + (float)a[1] * (float)a[1]
         + (float)b[0] * (float)b[0] + (float)b[1] * (float)b[1];
#endif
}

#define PF 16   // prefetch depth (steps)

// Scan: 4 sequences/wave (16-lane rows), 4 dims/lane (f16x4), packed-f16
// state, 4-hop row-local DPP butterfly, rsq. PF-deep register ring.
__global__ __launch_bounds__(64) void scan_kernel(const f16* __restrict__ Kv,
                                                  const f16* __restrict__ Gv,
                                                  f16* __restrict__ Ov)
{
    const int w = blockIdx.x;     // 0..31
    const int l = threadIdx.x;

    const size_t base = (size_t)(w >> 2) * (SEQL * DIM) + (size_t)((w & 3) * 256 + l * 4);
    f16x2 h01 = (f16x2){(f16)0.f, (f16)0.f};
    f16x2 h23 = (f16x2){(f16)0.f, (f16)0.f};

    f16x4 kb[PF], gb[PF];
    #pragma unroll
    for (int u = 0; u < PF; ++u) {
        kb[u] = *(const f16x4*)(Kv + base + (size_t)u * DIM);
        gb[u] = *(const f16x4*)(Gv + base + (size_t)u * DIM);
    }

    size_t off = base;

    #define SCAN_STEP(kc, gc)                                                          \
        do {                                                                           \
            const f16x2 k01 = __builtin_shufflevector((kc), (kc), 0, 1);               \
            const f16x2 k23 = __builtin_shufflevector((kc), (kc), 2, 3);               \
            const f16x2 g01 = __builtin_shufflevector((gc), (gc), 0, 1);               \
            const f16x2 g23 = __builtin_shufflevector((gc), (gc), 2, 3);               \
            const f16x2 u01 = h01 * g01;                                               \
            const f16x2 u23 = h23 * g23;                                               \
            float s = sumsq4(h01, h23);                                                \
            s = dpp_add_f<0xB1>(s);                                                    \
            s = dpp_add_f<0x4E>(s);                                                    \
            s = dpp_add_f<0x141>(s);                                                   \
            s = dpp_add_f<0x140>(s);                                                   \
            const float inv = __builtin_amdgcn_rsqf(fmaf(s, 0.015625f, 1e-8f));        \
            const f16 ih = (f16)inv;                                                   \
            const f16x2 iv = (f16x2){ih, ih};                                          \
            h01 = u01 * iv + k01;                                                      \
            h23 = u23 * iv + k23;                                                      \
            f16x4 o;                                                                   \
            o[0] = h01[0]; o[1] = h01[1]; o[2] = h23[0]; o[3] = h23[1];                \
            *(f16x4*)(Ov + off) = o;                                                   \
            off += DIM;                                                                \
        } while (0)

    for (int t0 = 0; t0 + PF < SEQL; t0 += PF) {
        #pragma unroll
        for (int u = 0; u < PF; ++u) {
            const f16x4 kc = kb[u], gc = gb[u];
            const size_t poff = off + (size_t)PF * DIM;
            kb[u] = *(const f16x4*)(Kv + poff);
            gb[u] = *(const f16x4*)(Gv + poff);
            SCAN_STEP(kc, gc);
        }
    }
    #pragma unroll
    for (int u = 0; u < PF; ++u) {
        const f16x4 kc = kb[u], gc = gb[u];
        SCAN_STEP(kc, gc);
    }
    #undef SCAN_STEP
}

// ---------------------------------------------------------------------------
extern "C" void kernel_launch(void* const* d_in, const int* in_sizes, int n_in,
                              void* d_out, int out_size, void* d_ws, size_t ws_size,
                              hipStream_t stream) {
    const float* x    = (const float*)d_in[0];
    const float* Wk   = (const float*)d_in[1];
    const float* Wkg  = (const float*)d_in[2];
    const float* bkg  = (const float*)d_in[3];
    const float* Wout = (const float*)d_in[4];
    float* out = (float*)d_out;

    // workspace (f16): xh/Kh/Gh 32MB each + Wcat 4MB + Wout 2MB = 102MB
    f16* xh    = (f16*)d_ws;                         // [M, D]; scan output reuses it
    f16* Kh    = xh    + (size_t)MROWS * DIM;
    f16* Gh    = Kh    + (size_t)MROWS * DIM;
    f16* Wcat  = Gh    + (size_t)MROWS * DIM;        // [2048, 1024]: Wk ; Wkg
    f16* Wouth = Wcat  + (size_t)2 * DIM * DIM;

    const int nx8 = MROWS * DIM / 8;
    const int nw8 = DIM * DIM / 8;
    cvt_f32_f16<<<dim3(nx8 / 256), dim3(256), 0, stream>>>(x, xh, nx8);
    cvt_f32_f16<<<dim3(nw8 / 256), dim3(256), 0, stream>>>(Wk, Wcat, nw8);
    cvt_f32_f16<<<dim3(nw8 / 256), dim3(256), 0, stream>>>(Wkg, Wcat + (size_t)DIM * DIM, nw8);
    cvt_f32_f16<<<dim3(nw8 / 256), dim3(256), 0, stream>>>(Wout, Wouth, nw8);

    // fused k|g GEMM: M=16384, N=2048 -> 64 x 8 = 512 blocks
    gemm8<1><<<dim3(512), dim3(512), 0, stream>>>(xh, Wcat, bkg, Kh, Gh);
    // scan: o -> xh
    scan_kernel<<<dim3(32), dim3(64), 0, stream>>>(Kh, Gh, xh);
    // out = o @ Wout.T: 64 x 4 = 256 blocks
    gemm8<0><<<dim3(256), dim3(512), 0, stream>>>(xh, Wouth, nullptr, out, nullptr);
}